// Round 3
// baseline (123.680 us; speedup 1.0000x reference)
//
#include <hip/hip_runtime.h>

// ContrastiveLoss cosine: B=4096 rows, D=1024, fp32.
// out layout: [0]=loss, [1..B]=i2t_cosine, [1+B..2B]=t2i_cosine (identical values).
// Single fused kernel: per-row dots + candidate norms in one read pass, then
// last-block-finishes deterministic reduction (device-scope fences, Guideline 16).
// ws layout: counter (uint, offset 0), partials[1024] floats at byte offset 128.

constexpr int B = 4096;
constexpr int D = 1024;
constexpr int NBLK = B / 4;   // 1024 blocks, 4 rows (one wave each) per block
#define EPSF 1e-8f
#define MARGIN 0.2f

__device__ __forceinline__ float waveReduceSum(float v) {
#pragma unroll
    for (int off = 32; off > 0; off >>= 1)
        v += __shfl_xor(v, off, 64);
    return v;
}

__device__ __forceinline__ float dot4(float4 a, float4 b) {
    return a.x * b.x + a.y * b.y + a.z * b.z + a.w * b.w;
}

__global__ __launch_bounds__(256) void fused_all(
    const float* __restrict__ img, const float* __restrict__ txt,
    const int* __restrict__ ci, const int* __restrict__ ct,
    float* __restrict__ out,
    unsigned int* __restrict__ counter, float* __restrict__ partials) {
    __shared__ float strip[4];     // per-wave triplet values
    __shared__ float sflag;        // "am I the last block"
    __shared__ float sred[256];    // final-reduce scratch
    const int wave = threadIdx.x >> 6;
    const int lane = threadIdx.x & 63;
    const int row = blockIdx.x * 4 + wave;

    const int c0 = ci[row * 2 + 0];
    const int c1 = ci[row * 2 + 1];
    const int e0 = ct[row * 2 + 0];
    const int e1 = ct[row * 2 + 1];

    const float4* __restrict__ ib = (const float4*)(img + (size_t)row * D);
    const float4* __restrict__ tb = (const float4*)(txt + (size_t)row * D);
    const float4* __restrict__ i0 = (const float4*)(img + (size_t)c0 * D);
    const float4* __restrict__ i1 = (const float4*)(img + (size_t)c1 * D);
    const float4* __restrict__ t0 = (const float4*)(txt + (size_t)e0 * D);
    const float4* __restrict__ t1 = (const float4*)(txt + (size_t)e1 * D);

    // 11 dot-products over D=1024 in one pass over 6 rows:
    //   sd = img.txt, s1 = |img|^2, s2 = |txt|^2
    //   a0/a1 = txt.img[c], q0/q1 = |img[c]|^2   (t2i negatives)
    //   a2/a3 = img.txt[e], r0/r1 = |txt[e]|^2   (i2t negatives)
    float sd = 0.f, s1 = 0.f, s2 = 0.f;
    float a0 = 0.f, a1 = 0.f, a2 = 0.f, a3 = 0.f;
    float q0 = 0.f, q1 = 0.f, r0 = 0.f, r1 = 0.f;
#pragma unroll
    for (int j = 0; j < 4; ++j) {
        const int idx = j * 64 + lane;  // 256 float4 per row
        float4 A = ib[idx];
        float4 T = tb[idx];
        float4 X0 = i0[idx];
        float4 X1 = i1[idx];
        float4 Y0 = t0[idx];
        float4 Y1 = t1[idx];
        sd += dot4(A, T);
        s1 += dot4(A, A);
        s2 += dot4(T, T);
        a0 += dot4(T, X0);
        q0 += dot4(X0, X0);
        a1 += dot4(T, X1);
        q1 += dot4(X1, X1);
        a2 += dot4(A, Y0);
        r0 += dot4(Y0, Y0);
        a3 += dot4(A, Y1);
        r1 += dot4(Y1, Y1);
    }
    sd = waveReduceSum(sd);
    s1 = waveReduceSum(s1);
    s2 = waveReduceSum(s2);
    a0 = waveReduceSum(a0);
    a1 = waveReduceSum(a1);
    a2 = waveReduceSum(a2);
    a3 = waveReduceSum(a3);
    q0 = waveReduceSum(q0);
    q1 = waveReduceSum(q1);
    r0 = waveReduceSum(r0);
    r1 = waveReduceSum(r1);

    if (lane == 0) {
        const float na = sqrtf(s1);   // ||img[row]||
        const float nb = sqrtf(s2);   // ||txt[row]||
        const float prod = na * nb;
        const float cosv = sd / prod;                    // unclamped (sim)
        const float pos = 1.f - sd / fmaxf(prod, EPSF);  // clamped (dist)
        // t2i negative: anchor txt[row] vs img candidates ('<=': later wins ties)
        const float d0 = 1.f - a0 / fmaxf(nb * sqrtf(q0), EPSF);
        const float d1 = 1.f - a1 / fmaxf(nb * sqrtf(q1), EPSF);
        const float t2i_neg = (d1 <= d0) ? d1 : d0;
        // i2t negative: anchor img[row] vs txt candidates
        const float g0 = 1.f - a2 / fmaxf(na * sqrtf(r0), EPSF);
        const float g1 = 1.f - a3 / fmaxf(na * sqrtf(r1), EPSF);
        const float i2t_neg = (g1 <= g0) ? g1 : g0;

        out[1 + row] = cosv;          // i2t_cosine
        out[1 + B + row] = cosv;      // t2i_cosine (identical by construction)
        strip[wave] = fmaxf(pos - i2t_neg + MARGIN, 0.f)
                    + fmaxf(pos - t2i_neg + MARGIN, 0.f);
    }
    __syncthreads();

    // Block partial -> global; last block (device-scope counter) reduces all.
    if (threadIdx.x == 0) {
        partials[blockIdx.x] = strip[0] + strip[1] + strip[2] + strip[3];
        __threadfence();  // release: partial visible before count bump (cross-XCD)
        unsigned int old = atomicAdd(counter, 1u);
        sflag = (old == NBLK - 1) ? 1.0f : 0.0f;
    }
    __syncthreads();

    if (sflag != 0.0f) {
        __threadfence();  // acquire: all partials visible
        const int t = threadIdx.x;
        // fixed-order, bit-deterministic reduction of 1024 partials
        float v = partials[t] + partials[t + 256] + partials[t + 512] + partials[t + 768];
        sred[t] = v;
        __syncthreads();
#pragma unroll
        for (int off = 128; off >= 64; off >>= 1) {
            if (t < off) sred[t] += sred[t + off];
            __syncthreads();
        }
        if (t < 64) {
            float x = sred[t];
            x = waveReduceSum(x);
            if (t == 0) out[0] = x * (1.0f / (float)B);
        }
    }
}

extern "C" void kernel_launch(void* const* d_in, const int* in_sizes, int n_in,
                              void* d_out, int out_size, void* d_ws, size_t ws_size,
                              hipStream_t stream) {
    const float* img = (const float*)d_in[0];
    const float* txt = (const float*)d_in[1];
    // d_in[2]=labels (unused), d_in[3]=locations (unused)
    const int* ci = (const int*)d_in[4];
    const int* ct = (const int*)d_in[5];
    float* out = (float*)d_out;

    unsigned int* counter = (unsigned int*)d_ws;
    float* partials = (float*)((char*)d_ws + 128);  // own cacheline, away from counter

    hipMemsetAsync(counter, 0, sizeof(unsigned int), stream);  // graph-capture-safe
    fused_all<<<NBLK, 256, 0, stream>>>(img, txt, ci, ct, out, counter, partials);
}

// Round 4
// 96.084 us; speedup vs baseline: 1.2872x; 1.2872x over previous
//
#include <hip/hip_runtime.h>

// ContrastiveLoss cosine: B=4096 rows, D=1024, fp32.
// out layout: [0]=loss, [1..B]=i2t_cosine, [1+B..2B]=t2i_cosine (identical values).
// ws layout (floats): trip[B].
//
// Latency-bound fix (round-3 counters: 11% HBM, 6.5% VALU, 31% occ):
//  - one 256-thread block per row -> 4096 blocks, 16384 waves (2x oversubscribe)
//  - D=1024 = 256 threads x 1 float4: NO k-loop, 6 independent loads per thread
//  - tail loss-reduce back in its own tiny kernel (round-3's in-kernel
//    fence+atomic tail cost ~30 us; reverted)

constexpr int B = 4096;
constexpr int D = 1024;
#define EPSF 1e-8f
#define MARGIN 0.2f

__device__ __forceinline__ float waveReduceSum(float v) {
#pragma unroll
    for (int off = 32; off > 0; off >>= 1)
        v += __shfl_xor(v, off, 64);
    return v;
}

__device__ __forceinline__ float dot4(float4 a, float4 b) {
    return a.x * b.x + a.y * b.y + a.z * b.z + a.w * b.w;
}

// One block per row. Each thread owns exactly one float4 (16B) of each of the
// 6 involved rows; all 6 loads are independent and issue back-to-back.
__global__ __launch_bounds__(256) void fused_rows(
    const float* __restrict__ img, const float* __restrict__ txt,
    const int* __restrict__ ci, const int* __restrict__ ct,
    float* __restrict__ out, float* __restrict__ trip) {
    const int row = blockIdx.x;
    const int t = threadIdx.x;      // 0..255 -> float4 index within row
    const int wave = t >> 6;
    const int lane = t & 63;

    const int c0 = ci[row * 2 + 0];
    const int c1 = ci[row * 2 + 1];
    const int e0 = ct[row * 2 + 0];
    const int e1 = ct[row * 2 + 1];

    const float4 A  = ((const float4*)(img + (size_t)row * D))[t];
    const float4 T  = ((const float4*)(txt + (size_t)row * D))[t];
    const float4 X0 = ((const float4*)(img + (size_t)c0 * D))[t];
    const float4 X1 = ((const float4*)(img + (size_t)c1 * D))[t];
    const float4 Y0 = ((const float4*)(txt + (size_t)e0 * D))[t];
    const float4 Y1 = ((const float4*)(txt + (size_t)e1 * D))[t];

    // 11 partial dot-products:
    //   [0] img.txt  [1] |img|^2  [2] |txt|^2
    //   [3] txt.img[c0] [4] txt.img[c1] [5] |img[c0]|^2 [6] |img[c1]|^2
    //   [7] img.txt[e0] [8] img.txt[e1] [9] |txt[e0]|^2 [10] |txt[e1]|^2
    float v[11];
    v[0] = dot4(A, T);
    v[1] = dot4(A, A);
    v[2] = dot4(T, T);
    v[3] = dot4(T, X0);
    v[4] = dot4(T, X1);
    v[5] = dot4(X0, X0);
    v[6] = dot4(X1, X1);
    v[7] = dot4(A, Y0);
    v[8] = dot4(A, Y1);
    v[9] = dot4(Y0, Y0);
    v[10] = dot4(Y1, Y1);

#pragma unroll
    for (int i = 0; i < 11; ++i) v[i] = waveReduceSum(v[i]);

    __shared__ float s[4][11];
    if (lane == 0) {
#pragma unroll
        for (int i = 0; i < 11; ++i) s[wave][i] = v[i];
    }
    __syncthreads();

    if (t == 0) {
        float f[11];
#pragma unroll
        for (int i = 0; i < 11; ++i)
            f[i] = s[0][i] + s[1][i] + s[2][i] + s[3][i];

        const float na = sqrtf(f[1]);   // ||img[row]||
        const float nb = sqrtf(f[2]);   // ||txt[row]||
        const float prod = na * nb;
        const float cosv = f[0] / prod;                    // unclamped (sim)
        const float pos = 1.f - f[0] / fmaxf(prod, EPSF);  // clamped (dist)
        // t2i negative: anchor txt[row] vs img candidates ('<=': later wins ties)
        const float d0 = 1.f - f[3] / fmaxf(nb * sqrtf(f[5]), EPSF);
        const float d1 = 1.f - f[4] / fmaxf(nb * sqrtf(f[6]), EPSF);
        const float t2i_neg = (d1 <= d0) ? d1 : d0;
        // i2t negative: anchor img[row] vs txt candidates
        const float g0 = 1.f - f[7] / fmaxf(na * sqrtf(f[9]), EPSF);
        const float g1 = 1.f - f[8] / fmaxf(na * sqrtf(f[10]), EPSF);
        const float i2t_neg = (g1 <= g0) ? g1 : g0;

        out[1 + row] = cosv;          // i2t_cosine
        out[1 + B + row] = cosv;      // t2i_cosine (identical by construction)
        trip[row] = fmaxf(pos - i2t_neg + MARGIN, 0.f)
                  + fmaxf(pos - t2i_neg + MARGIN, 0.f);
    }
}

// Deterministic reduction of trip[B] -> loss = sum / B.
__global__ __launch_bounds__(1024) void k_reduce(
    const float* __restrict__ trip, float* __restrict__ out) {
    __shared__ float s[1024];
    const int t = threadIdx.x;
    float v = trip[t] + trip[t + 1024] + trip[t + 2048] + trip[t + 3072];
    s[t] = v;
    __syncthreads();
#pragma unroll
    for (int off = 512; off >= 64; off >>= 1) {
        if (t < off) s[t] += s[t + off];
        __syncthreads();
    }
    if (t < 64) {
        float x = s[t];
        x = waveReduceSum(x);
        if (t == 0) out[0] = x * (1.0f / (float)B);
    }
}

extern "C" void kernel_launch(void* const* d_in, const int* in_sizes, int n_in,
                              void* d_out, int out_size, void* d_ws, size_t ws_size,
                              hipStream_t stream) {
    const float* img = (const float*)d_in[0];
    const float* txt = (const float*)d_in[1];
    // d_in[2]=labels (unused), d_in[3]=locations (unused)
    const int* ci = (const int*)d_in[4];
    const int* ct = (const int*)d_in[5];
    float* out = (float*)d_out;
    float* trip = (float*)d_ws;

    fused_rows<<<B, 256, 0, stream>>>(img, txt, ci, ct, out, trip);
    k_reduce<<<1, 1024, 0, stream>>>(trip, out);
}